// Round 13
// baseline (734.350 us; speedup 1.0000x reference)
//
#include <hip/hip_runtime.h>
#include <cstdint>
#include <cstddef>
#include <math.h>

#define M_ROWS 16384
#define N_COLS 1000
#define N_PAD  1024
#define K_DIM  4096
#define NUM_TTA 64
#define KEPT 6
#define BATCH 256
#define NKT (K_DIM / 32)       // 128 K-tiles of 32

typedef __attribute__((ext_vector_type(8))) short short8;
typedef __attribute__((ext_vector_type(4))) float v4f;

#define GL_LDS16(g, l)                                                        \
    __builtin_amdgcn_global_load_lds(                                         \
        (const __attribute__((address_space(1))) unsigned int*)(g),           \
        (__attribute__((address_space(3))) unsigned int*)(l), 16, 0, 0)

// ---- RNE bf16 split via HW cvt: x = hi + lo (+ ~2^-18 rel) ----
__device__ __forceinline__ void split2(float x, unsigned short& h, unsigned short& l) {
    const __bf16 hb = (__bf16)x;
    const float hf  = (float)hb;
    const __bf16 lb = (__bf16)(x - hf);
    h = __builtin_bit_cast(unsigned short, hb);
    l = __builtin_bit_cast(unsigned short, lb);
}

// 8 floats -> 8 hi bf16 + 8 lo bf16
__device__ __forceinline__ void split8(const float4& a, const float4& b,
                                       short8& hv, short8& lv) {
    unsigned short h, l;
    split2(a.x, h, l); hv[0] = (short)h; lv[0] = (short)l;
    split2(a.y, h, l); hv[1] = (short)h; lv[1] = (short)l;
    split2(a.z, h, l); hv[2] = (short)h; lv[2] = (short)l;
    split2(a.w, h, l); hv[3] = (short)h; lv[3] = (short)l;
    split2(b.x, h, l); hv[4] = (short)h; lv[4] = (short)l;
    split2(b.y, h, l); hv[5] = (short)h; lv[5] = (short)l;
    split2(b.z, h, l); hv[6] = (short)h; lv[6] = (short)l;
    split2(b.w, h, l); hv[7] = (short)h; lv[7] = (short)l;
}

// ---- inline f64 exp for d <= 0 (vote-side merge only; 16 calls/thread) ----
__device__ __forceinline__ double exp_neg(double d) {
    if (d < -700.0) return 0.0;
    const double kd = rint(d * 1.4426950408889634074);
    double r = fma(-kd, 6.93147180369123816490e-01, d);
    r = fma(-kd, 1.90821492927058770002e-10, r);
    double p = 2.08767569878680989792e-09;      // 1/12!
    p = fma(p, r, 2.50521083854417187751e-08);  // 1/11!
    p = fma(p, r, 2.75573192239858906526e-07);  // 1/10!
    p = fma(p, r, 2.75573192239858925110e-06);  // 1/9!
    p = fma(p, r, 2.48015873015873015873e-05);  // 1/8!
    p = fma(p, r, 1.98412698412698412526e-04);  // 1/7!
    p = fma(p, r, 1.38888888888888894069e-03);  // 1/6!
    p = fma(p, r, 8.33333333333333321769e-03);  // 1/5!
    p = fma(p, r, 4.16666666666666643537e-02);  // 1/4!
    p = fma(p, r, 1.66666666666666657415e-01);  // 1/3!
    p = fma(p, r, 5.0e-01);
    p = fma(p, r, 1.0);
    p = fma(p, r, 1.0);
    const long long k = (long long)kd;
    return p * __longlong_as_double((1023LL + k) << 52);
}

// ---------------- W: transpose 4096x1000 -> [n][k] 1024x4096, split ----------------
__global__ __launch_bounds__(1024)
void split_w(const float* __restrict__ W, unsigned short* __restrict__ Wh,
             unsigned short* __restrict__ Wl)
{
    __shared__ float tile[32][33];
    const int k0 = blockIdx.x * 32, n0 = blockIdx.y * 32;
    const int tx = threadIdx.x, ty = threadIdx.y;
    const int n = n0 + tx, k = k0 + ty;
    tile[ty][tx] = (n < N_COLS) ? W[(size_t)k * N_COLS + n] : 0.f;
    __syncthreads();
    const float w = tile[tx][ty];           // = W[k0+tx][n0+ty]
    unsigned short h, l;
    split2(w, h, l);
    const size_t o = (size_t)(n0 + ty) * K_DIM + k0 + tx;
    Wh[o] = h; Wl[o] = l;
}

// ------------- GEMM + fused partial softmax stats -------------
// 256x256 tile, 512 thr = 8 waves (2m x 4n), wave = 128x64 out, BK=32,
// 16x16x32 MFMA.  Round-13 change: CARRY-ACROSS-BARRIER MFMA DEFERRAL.
// The last 24 MFMAs of tile k (MCLM(2),MCLM(3); 12 live frags, within the
// existing 16-frag live set) execute AFTER tile k+1's barrier: they depend
// only on registers, so they issue into the MFMA pipe immediately while
// the LDS port serves the new tile's read burst -- the first mechanism
// that overlaps port and MFMA without any post-barrier read dependency.
// Per-acc MFMA chain order preserved (K-ascending) -> bit-identical.
__global__ __launch_bounds__(512, 2)
void gemm_mfma(const float* __restrict__ X,
               const unsigned short* __restrict__ Bh_, const unsigned short* __restrict__ Bl_,
               const float* __restrict__ bias, double* __restrict__ part,
               int m_tiles)
{
    __shared__ __attribute__((aligned(16))) char smem[2 * 4 * 16384];

    const int t    = threadIdx.x;
    const int lane = t & 63;
    const int wave = t >> 6;
    const int wr   = wave >> 2;        // 0..1  m-half of block tile
    const int wc   = wave & 3;         // 0..3  n-quarter
    const int ml   = lane & 15;
    const int kh   = lane >> 4;        // k-slot (8 bf16 each)

    // ---- XCD swizzle ----
    const int bid  = blockIdx.x;
    const int xcd  = bid & 7;
    const int slot = bid >> 3;
    const int mt   = xcd * (m_tiles >> 3) + (slot >> 2);
    const int nt   = slot & 3;
    const int m0 = mt * 256, n0 = nt * 256;

    // ---- B staging (global_load_lds, pre-swizzled source) ----
    const int    schunk = (t & 3) ^ ((t >> 3) & 3);
    const size_t ro     = (size_t)(t >> 2) * (K_DIM * 2) + (size_t)schunk * 16;
    const char* gBh = (const char*)Bh_ + (size_t)n0 * (K_DIM * 2) + ro;
    const char* gBl = (const char*)Bl_ + (size_t)n0 * (K_DIM * 2) + ro;
    char* ldst = smem + t * 16;
    const size_t RSTEP = (size_t)128 * K_DIM * 2;   // +128 rows

    // ---- A staging (reg path): thread t covers row ar, 16-float half ahalf ----
    const int ar    = t >> 1;          // 0..255
    const int ahalf = t & 1;           // k 0-15 or 16-31 within tile
    const float* gA = X + (size_t)(m0 + ar) * K_DIM + ahalf * 16;
    const int sig = (ar >> 1) & 3;     // row swizzle key (matches reader)
    const int s0  = (ahalf * 2) ^ sig;
    const int s1  = (ahalf * 2 + 1) ^ sig;
    const int aw0 = ar * 64 + (s0 << 4);   // LDS byte off in A panel, floats 0-7
    const int aw1 = ar * 64 + (s1 << 4);   // floats 8-15

    // ---- per-lane LDS read bases (bytes within one 16KB mat panel) ----
    const int swz = ((kh ^ (ml >> 1)) & 3) << 4;
    const int lbA = wr * 8192 + ml * 64 + swz;
    const int lbB = wc * 4096 + ml * 64 + swz;

    v4f acc[8][4];
#pragma unroll
    for (int i = 0; i < 8; ++i)
#pragma unroll
        for (int j = 0; j < 4; ++j) acc[i][j] = (v4f){0.f, 0.f, 0.f, 0.f};

#define FRAG(P) (*(const short8*)(smem + (P)))
#define SB __builtin_amdgcn_sched_barrier(0)

    short8 ah[4], al[4], bh[4], bl[4];

    // ---------------- prologue: stage K-tile 0 into buf 0 ----------------
    {
        const float4 fa = *(const float4*)(gA);
        const float4 fb = *(const float4*)(gA + 4);
        const float4 fc = *(const float4*)(gA + 8);
        const float4 fd = *(const float4*)(gA + 12);
        GL_LDS16(gBh,         ldst + 32768);
        GL_LDS16(gBh + RSTEP, ldst + 40960);
        GL_LDS16(gBl,         ldst + 49152);
        GL_LDS16(gBl + RSTEP, ldst + 57344);
        short8 hv, lv;
        split8(fa, fb, hv, lv);
        *(short8*)(smem + aw0) = hv;
        *(short8*)(smem + 16384 + aw0) = lv;
        split8(fc, fd, hv, lv);
        *(short8*)(smem + aw1) = hv;
        *(short8*)(smem + 16384 + aw1) = lv;
    }
    __syncthreads();

#define RD_B(NF) do {                                                         \
    bh[NF] = FRAG(B0 + 32768 + (NF) * 1024 + lbB);                            \
    bl[NF] = FRAG(B0 + 49152 + (NF) * 1024 + lbB);                            \
} while (0)
#define RD_A(MF, HO) do {                                                     \
    ah[MF] = FRAG(B0 + (HO) +         (MF) * 1024 + lbA);                     \
    al[MF] = FRAG(B0 + (HO) + 16384 + (MF) * 1024 + lbA);                     \
} while (0)
#define MCLN(NF) do {                                                         \
    __builtin_amdgcn_s_setprio(1);                                            \
    _Pragma("unroll")                                                         \
    for (int mf = 0; mf < 4; ++mf)                                            \
        acc[mf][NF] = __builtin_amdgcn_mfma_f32_16x16x32_bf16(ah[mf], bl[NF], acc[mf][NF], 0, 0, 0); \
    _Pragma("unroll")                                                         \
    for (int mf = 0; mf < 4; ++mf)                                            \
        acc[mf][NF] = __builtin_amdgcn_mfma_f32_16x16x32_bf16(al[mf], bh[NF], acc[mf][NF], 0, 0, 0); \
    _Pragma("unroll")                                                         \
    for (int mf = 0; mf < 4; ++mf)                                            \
        acc[mf][NF] = __builtin_amdgcn_mfma_f32_16x16x32_bf16(ah[mf], bh[NF], acc[mf][NF], 0, 0, 0); \
    __builtin_amdgcn_s_setprio(0);                                            \
} while (0)
#define MCLM(MF) do {                                                         \
    __builtin_amdgcn_s_setprio(1);                                            \
    _Pragma("unroll")                                                         \
    for (int nf = 0; nf < 4; ++nf)                                            \
        acc[4 + (MF)][nf] = __builtin_amdgcn_mfma_f32_16x16x32_bf16(ah[MF], bl[nf], acc[4 + (MF)][nf], 0, 0, 0); \
    _Pragma("unroll")                                                         \
    for (int nf = 0; nf < 4; ++nf)                                            \
        acc[4 + (MF)][nf] = __builtin_amdgcn_mfma_f32_16x16x32_bf16(al[MF], bh[nf], acc[4 + (MF)][nf], 0, 0, 0); \
    _Pragma("unroll")                                                         \
    for (int nf = 0; nf < 4; ++nf)                                            \
        acc[4 + (MF)][nf] = __builtin_amdgcn_mfma_f32_16x16x32_bf16(ah[MF], bh[nf], acc[4 + (MF)][nf], 0, 0, 0); \
    __builtin_amdgcn_s_setprio(0);                                            \
} while (0)

// Tile body.  PREV=1: first execute the DEFERRED MCLM(2),MCLM(3) of the
// previous tile (held frags: ah[2],ah[3],al[2],al[3],bh[0-3],bl[0-3]) right
// after the barrier, overlapping the new tile's read burst.  Ends by reading
// m-half-1 frags 2,3 and DEFERRING their MFMAs to the next tile.
#define TILE_X(KT, RB, PREV) do {                                             \
    const int B0 = (RB) * 65536;                                              \
    const int B1 = ((RB) ^ 1) * 65536;                                        \
    asm volatile("s_waitcnt vmcnt(0) lgkmcnt(0)" ::: "memory");               \
    __builtin_amdgcn_s_barrier();                                             \
    SB;                                                                       \
    const bool pf = (KT) + 1 < NKT;                                           \
    float4 fa, fb;                                                            \
    if (pf) {   /* issue next tile's loads: A 8 floats + B GL_LDS */          \
        const float* ga_ = gA + ((KT) + 1) * 32;                              \
        fa = *(const float4*)(ga_);                                           \
        fb = *(const float4*)(ga_ + 4);                                       \
        const int kb_ = ((KT) + 1) * 64;                                      \
        GL_LDS16(gBh + kb_,         ldst + B1 + 32768);                       \
        GL_LDS16(gBh + RSTEP + kb_, ldst + B1 + 40960);                       \
        GL_LDS16(gBl + kb_,         ldst + B1 + 49152);                       \
        GL_LDS16(gBl + RSTEP + kb_, ldst + B1 + 57344);                       \
    }                                                                         \
    /* new A m-half-0 frags 0,1 into the 4 free frag regs */                  \
    RD_A(0, 0); RD_A(1, 0);                                                   \
    SB;                                                                       \
    if (PREV) {   /* deferred prev-tile MFMAs: register-only, no read dep */  \
        MCLM(2); MCLM(3);                                                     \
    }                                                                         \
    SB;                                                                       \
    /* now the held regs are free: read the rest of this tile */              \
    RD_A(2, 0); RD_A(3, 0);                                                   \
    RD_B(0); RD_B(1); RD_B(2); RD_B(3);                                       \
    SB;                                                                       \
    MCLN(0); SB;                                                              \
    MCLN(1); SB;                                                              \
    if (pf) {   /* split floats 0-7 -> write; then load floats 8-15 */        \
        short8 hv, lv;                                                        \
        split8(fa, fb, hv, lv);                                               \
        *(short8*)(smem + B1 + aw0) = hv;                                     \
        *(short8*)(smem + B1 + 16384 + aw0) = lv;                             \
        const float* ga_ = gA + ((KT) + 1) * 32 + 8;                          \
        fa = *(const float4*)(ga_);                                           \
        fb = *(const float4*)(ga_ + 4);                                       \
    }                                                                         \
    SB;                                                                       \
    MCLN(2); SB;                                                              \
    MCLN(3); SB;                                                              \
    RD_A(0, 4096); RD_A(1, 4096); SB;                                         \
    MCLM(0); SB;                                                              \
    if (pf) {   /* split floats 8-15 -> write */                              \
        short8 hv, lv;                                                        \
        split8(fa, fb, hv, lv);                                               \
        *(short8*)(smem + B1 + aw1) = hv;                                     \
        *(short8*)(smem + B1 + 16384 + aw1) = lv;                             \
    }                                                                         \
    SB;                                                                       \
    MCLM(1); SB;                                                              \
    /* read m-half-1 frags 2,3; their 24 MFMAs are DEFERRED past the */       \
    /* next barrier (regs held; buf[RB] not overwritten until tile KT+1) */   \
    RD_A(2, 4096); RD_A(3, 4096);                                             \
} while (0)

    TILE_X(0, 0, 0);
#pragma unroll 1
    for (int kt = 1; kt + 1 < NKT; kt += 2) {
        TILE_X(kt, 1, 1);
        TILE_X(kt + 1, 0, 1);
    }
    TILE_X(NKT - 1, 1, 1);
    // trailing deferred MFMAs of the last tile (registers only)
    asm volatile("s_waitcnt lgkmcnt(0)");
    SB;
    MCLM(2); MCLM(3);

    // ---- fused epilogue: per-(row, chunk) online-softmax partials ----
    // C/D layout: col = lane&15 (ml), row = kh*4 + reg  [m89/m91].
    // chunk = nt*4 + wc covers cols chunk*64 .. +63; stats reduced across
    // the 16-lane half-group (shfl_xor 8,4,2,1 stays in group), f32 trees.
    const int chunk = nt * 4 + wc;
    const int colbase = n0 + wc * 64;
    float bcol[4]; bool bval[4];
#pragma unroll
    for (int ni = 0; ni < 4; ++ni) {
        const int col = colbase + ni * 16 + ml;
        bval[ni] = (col < N_COLS);
        bcol[ni] = bval[ni] ? bias[col] : 0.f;
    }
#pragma unroll
    for (int mi = 0; mi < 8; ++mi) {
        const int rbase = m0 + wr * 128 + (mi >> 2) * 64 + (mi & 3) * 16 + kh * 4;
#pragma unroll
        for (int r = 0; r < 4; ++r) {
            float x[4];
            float bv = -3.0e38f; int bi = 0;
#pragma unroll
            for (int ni = 0; ni < 4; ++ni) {
                x[ni] = acc[mi][ni][r] + bcol[ni];
                const int col = colbase + ni * 16 + ml;
                if (bval[ni] && x[ni] > bv) { bv = x[ni]; bi = col; }
            }
#pragma unroll
            for (int s = 8; s > 0; s >>= 1) {
                const float ov = __shfl_xor(bv, s);
                const int   oi = __shfl_xor(bi, s);
                if (ov > bv || (ov == bv && oi < bi)) { bv = ov; bi = oi; }
            }
            float S = 0.f, T = 0.f;
#pragma unroll
            for (int ni = 0; ni < 4; ++ni) {
                if (bval[ni]) {
                    const float d = x[ni] - bv;         // <= 0
                    const float e = __expf(d);          // HW v_exp_f32
                    S += e;
                    T = fmaf(e, d, T);
                }
            }
#pragma unroll
            for (int s = 8; s > 0; s >>= 1) {
                S += __shfl_xor(S, s);
                T += __shfl_xor(T, s);
            }
            if (ml == 0) {
                double* pp = part + ((size_t)(rbase + r) * 16 + chunk) * 4;
                pp[0] = (double)S; pp[1] = (double)T;
                pp[2] = (double)bv; pp[3] = (double)bi;
            }
        }
    }
#undef TILE_X
#undef MCLM
#undef MCLN
#undef RD_A
#undef RD_B
#undef SB
#undef FRAG
}

// ------------- per-batch: merge partials, stable sort by entropy, tie loop -------------
__global__ __launch_bounds__(64)
void vote_kernel(const double* __restrict__ part, float* __restrict__ out)
{
    __shared__ double e[NUM_TTA];
    __shared__ int    sv[NUM_TTA];
    __shared__ float  counts[N_COLS];

    const int b = blockIdx.x;
    const int t = threadIdx.x;
    const int row = b * NUM_TTA + t;

    // ---- merge 16 chunk partials (ascending chunk = ascending cols) ----
    const double* pp = part + (size_t)row * 64;
    float m = -3.0e38f; int amax = 0;
#pragma unroll
    for (int c = 0; c < 16; ++c) {
        const float pm = (float)pp[c * 4 + 2];
        const int   pa = (int)pp[c * 4 + 3];
        if (pm > m) { m = pm; amax = pa; }   // strict > : earlier chunk (lower col) wins ties
    }
    double S = 0.0, T = 0.0;
#pragma unroll
    for (int c = 0; c < 16; ++c) {
        const double dm = (double)((float)pp[c * 4 + 2]) - (double)m;
        const double f  = exp_neg(dm);
        S += pp[c * 4 + 0] * f;
        T += (pp[c * 4 + 1] + dm * pp[c * 4 + 0]) * f;
    }
    e[t] = log(S) - T / S;
    const int myv = amax;
    for (int c = t; c < N_COLS; c += NUM_TTA) counts[c] = 0.f;
    __syncthreads();

    const double et = e[t];
    int rank = 0;
#pragma unroll
    for (int i = 0; i < NUM_TTA; ++i) {
        const double ei = e[i];
        rank += (ei < et) || (ei == et && i < t);
    }
    sv[rank] = myv;
    __syncthreads();

    if (t == 0) {
        for (int j = 0; j < KEPT; ++j) counts[sv[j]] += 1.f;
        float Mv = 0.f; int Tc = 0;
        for (int j = 0; j < KEPT; ++j) {
            const int c = sv[j];
            bool dup = false;
            for (int q = 0; q < j; ++q) dup = dup || (sv[q] == c);
            if (dup) continue;
            const float cv = counts[c];
            if (cv > Mv) { Mv = cv; Tc = 1; }
            else if (cv == Mv) { Tc += 1; }
        }
        for (int i = 0; i < NUM_TTA - KEPT; ++i) {
            if (Tc <= 1) break;
            const int c = sv[KEPT + i];
            const float oldc = counts[c];
            counts[c] = oldc + 1.f;
            if (oldc == Mv)            { Mv += 1.f; Tc = 1; }
            else if (oldc + 1.f == Mv) { Tc += 1; }
        }
    }
    __syncthreads();

    const size_t o0 = (size_t)b * N_COLS;
    for (int c = t; c < N_COLS; c += NUM_TTA)
        out[o0 + c] = logf(counts[c] * (1.f / 64.f) + 1e-8f);
}

// -------------------------------- launch --------------------------------
extern "C" void kernel_launch(void* const* d_in, const int* in_sizes, int n_in,
                              void* d_out, int out_size, void* d_ws, size_t ws_size,
                              hipStream_t stream) {
    const float* x    = (const float*)d_in[0];
    const float* Wm   = (const float*)d_in[1];
    const float* bias = (const float*)d_in[2];
    float* out = (float*)d_out;

    // ws layout: part f64[16384*16*4] (8 MB) | Wh,Wl bf16[1024*4096]
    char* p = (char*)d_ws;
    double* part = (double*)p;                     p += (size_t)M_ROWS * 16 * 4 * 8;
    unsigned short* Wh = (unsigned short*)p;       p += (size_t)N_PAD * K_DIM * 2;
    unsigned short* Wl = (unsigned short*)p;       p += (size_t)N_PAD * K_DIM * 2;

    split_w<<<dim3(K_DIM / 32, N_PAD / 32), dim3(32, 32), 0, stream>>>(Wm, Wh, Wl);

    const int m_tiles = M_ROWS / 256;   // 64, divisible by 8
    gemm_mfma<<<4 * m_tiles, 512, 0, stream>>>(
        x, Wh, Wl, bias, part, m_tiles);
    vote_kernel<<<BATCH, NUM_TTA, 0, stream>>>(part, out);
}

// Round 14
// 633.682 us; speedup vs baseline: 1.1589x; 1.1589x over previous
//
#include <hip/hip_runtime.h>
#include <cstdint>
#include <cstddef>
#include <math.h>

#define M_ROWS 16384
#define N_COLS 1000
#define N_PAD  1024
#define K_DIM  4096
#define NUM_TTA 64
#define KEPT 6
#define BATCH 256
#define NKT (K_DIM / 32)       // 128 K-tiles of 32

typedef __attribute__((ext_vector_type(8))) short short8;
typedef __attribute__((ext_vector_type(4))) float v4f;

#define GL_LDS16(g, l)                                                        \
    __builtin_amdgcn_global_load_lds(                                         \
        (const __attribute__((address_space(1))) unsigned int*)(g),           \
        (__attribute__((address_space(3))) unsigned int*)(l), 16, 0, 0)

// ---- RNE bf16 split via HW cvt: x = hi + lo (+ ~2^-18 rel) ----
__device__ __forceinline__ void split2(float x, unsigned short& h, unsigned short& l) {
    const __bf16 hb = (__bf16)x;
    const float hf  = (float)hb;
    const __bf16 lb = (__bf16)(x - hf);
    h = __builtin_bit_cast(unsigned short, hb);
    l = __builtin_bit_cast(unsigned short, lb);
}

// 8 floats -> 8 hi bf16 + 8 lo bf16
__device__ __forceinline__ void split8(const float4& a, const float4& b,
                                       short8& hv, short8& lv) {
    unsigned short h, l;
    split2(a.x, h, l); hv[0] = (short)h; lv[0] = (short)l;
    split2(a.y, h, l); hv[1] = (short)h; lv[1] = (short)l;
    split2(a.z, h, l); hv[2] = (short)h; lv[2] = (short)l;
    split2(a.w, h, l); hv[3] = (short)h; lv[3] = (short)l;
    split2(b.x, h, l); hv[4] = (short)h; lv[4] = (short)l;
    split2(b.y, h, l); hv[5] = (short)h; lv[5] = (short)l;
    split2(b.z, h, l); hv[6] = (short)h; lv[6] = (short)l;
    split2(b.w, h, l); hv[7] = (short)h; lv[7] = (short)l;
}

// ---- inline f64 exp for d <= 0 (vote-side merge only; 16 calls/thread) ----
__device__ __forceinline__ double exp_neg(double d) {
    if (d < -700.0) return 0.0;
    const double kd = rint(d * 1.4426950408889634074);
    double r = fma(-kd, 6.93147180369123816490e-01, d);
    r = fma(-kd, 1.90821492927058770002e-10, r);
    double p = 2.08767569878680989792e-09;      // 1/12!
    p = fma(p, r, 2.50521083854417187751e-08);  // 1/11!
    p = fma(p, r, 2.75573192239858906526e-07);  // 1/10!
    p = fma(p, r, 2.75573192239858925110e-06);  // 1/9!
    p = fma(p, r, 2.48015873015873015873e-05);  // 1/8!
    p = fma(p, r, 1.98412698412698412526e-04);  // 1/7!
    p = fma(p, r, 1.38888888888888894069e-03);  // 1/6!
    p = fma(p, r, 8.33333333333333321769e-03);  // 1/5!
    p = fma(p, r, 4.16666666666666643537e-02);  // 1/4!
    p = fma(p, r, 1.66666666666666657415e-01);  // 1/3!
    p = fma(p, r, 5.0e-01);
    p = fma(p, r, 1.0);
    p = fma(p, r, 1.0);
    const long long k = (long long)kd;
    return p * __longlong_as_double((1023LL + k) << 52);
}

// ---------------- W: transpose 4096x1000 -> [n][k] 1024x4096, split ----------------
__global__ __launch_bounds__(1024)
void split_w(const float* __restrict__ W, unsigned short* __restrict__ Wh,
             unsigned short* __restrict__ Wl)
{
    __shared__ float tile[32][33];
    const int k0 = blockIdx.x * 32, n0 = blockIdx.y * 32;
    const int tx = threadIdx.x, ty = threadIdx.y;
    const int n = n0 + tx, k = k0 + ty;
    tile[ty][tx] = (n < N_COLS) ? W[(size_t)k * N_COLS + n] : 0.f;
    __syncthreads();
    const float w = tile[tx][ty];           // = W[k0+tx][n0+ty]
    unsigned short h, l;
    split2(w, h, l);
    const size_t o = (size_t)(n0 + ty) * K_DIM + k0 + tx;
    Wh[o] = h; Wl[o] = l;
}

// ------------- GEMM + fused partial softmax stats -------------
// 256x256 tile, 512 thr = 8 waves (2m x 4n), wave = 128x64 out, BK=32,
// 16x16x32 MFMA, r7's fenced read/MFMA K-loop (measured best).
// r12 configuration (best measured: 635.2 us total, gemm ~369 us):
// fused epilogue with f32 HW exp + f32 reduction trees, partials stored f64.
__global__ __launch_bounds__(512, 2)
void gemm_mfma(const float* __restrict__ X,
               const unsigned short* __restrict__ Bh_, const unsigned short* __restrict__ Bl_,
               const float* __restrict__ bias, double* __restrict__ part,
               int m_tiles)
{
    __shared__ __attribute__((aligned(16))) char smem[2 * 4 * 16384];

    const int t    = threadIdx.x;
    const int lane = t & 63;
    const int wave = t >> 6;
    const int wr   = wave >> 2;        // 0..1  m-half of block tile
    const int wc   = wave & 3;         // 0..3  n-quarter
    const int ml   = lane & 15;
    const int kh   = lane >> 4;        // k-slot (8 bf16 each)

    // ---- XCD swizzle ----
    const int bid  = blockIdx.x;
    const int xcd  = bid & 7;
    const int slot = bid >> 3;
    const int mt   = xcd * (m_tiles >> 3) + (slot >> 2);
    const int nt   = slot & 3;
    const int m0 = mt * 256, n0 = nt * 256;

    // ---- B staging (global_load_lds, pre-swizzled source) ----
    const int    schunk = (t & 3) ^ ((t >> 3) & 3);
    const size_t ro     = (size_t)(t >> 2) * (K_DIM * 2) + (size_t)schunk * 16;
    const char* gBh = (const char*)Bh_ + (size_t)n0 * (K_DIM * 2) + ro;
    const char* gBl = (const char*)Bl_ + (size_t)n0 * (K_DIM * 2) + ro;
    char* ldst = smem + t * 16;
    const size_t RSTEP = (size_t)128 * K_DIM * 2;   // +128 rows

    // ---- A staging (reg path): thread t covers row ar, 16-float half ahalf ----
    const int ar    = t >> 1;          // 0..255
    const int ahalf = t & 1;           // k 0-15 or 16-31 within tile
    const float* gA = X + (size_t)(m0 + ar) * K_DIM + ahalf * 16;
    const int sig = (ar >> 1) & 3;     // row swizzle key (matches reader)
    const int s0  = (ahalf * 2) ^ sig;
    const int s1  = (ahalf * 2 + 1) ^ sig;
    const int aw0 = ar * 64 + (s0 << 4);   // LDS byte off in A panel, floats 0-7
    const int aw1 = ar * 64 + (s1 << 4);   // floats 8-15

    // ---- per-lane LDS read bases (bytes within one 16KB mat panel) ----
    const int swz = ((kh ^ (ml >> 1)) & 3) << 4;
    const int lbA = wr * 8192 + ml * 64 + swz;
    const int lbB = wc * 4096 + ml * 64 + swz;

    v4f acc[8][4];
#pragma unroll
    for (int i = 0; i < 8; ++i)
#pragma unroll
        for (int j = 0; j < 4; ++j) acc[i][j] = (v4f){0.f, 0.f, 0.f, 0.f};

#define FRAG(P) (*(const short8*)(smem + (P)))
#define SB __builtin_amdgcn_sched_barrier(0)

    short8 ah[4], al[4], bh[4], bl[4];

    // ---------------- prologue: stage K-tile 0 into buf 0 ----------------
    {
        const float4 fa = *(const float4*)(gA);
        const float4 fb = *(const float4*)(gA + 4);
        const float4 fc = *(const float4*)(gA + 8);
        const float4 fd = *(const float4*)(gA + 12);
        GL_LDS16(gBh,         ldst + 32768);
        GL_LDS16(gBh + RSTEP, ldst + 40960);
        GL_LDS16(gBl,         ldst + 49152);
        GL_LDS16(gBl + RSTEP, ldst + 57344);
        short8 hv, lv;
        split8(fa, fb, hv, lv);
        *(short8*)(smem + aw0) = hv;
        *(short8*)(smem + 16384 + aw0) = lv;
        split8(fc, fd, hv, lv);
        *(short8*)(smem + aw1) = hv;
        *(short8*)(smem + 16384 + aw1) = lv;
    }
    __syncthreads();

#define RD_B(NF) do {                                                         \
    bh[NF] = FRAG(B0 + 32768 + (NF) * 1024 + lbB);                            \
    bl[NF] = FRAG(B0 + 49152 + (NF) * 1024 + lbB);                            \
} while (0)
#define RD_A(MF, HO) do {                                                     \
    ah[MF] = FRAG(B0 + (HO) +         (MF) * 1024 + lbA);                     \
    al[MF] = FRAG(B0 + (HO) + 16384 + (MF) * 1024 + lbA);                     \
} while (0)
#define MCLN(NF) do {                                                         \
    __builtin_amdgcn_s_setprio(1);                                            \
    _Pragma("unroll")                                                         \
    for (int mf = 0; mf < 4; ++mf)                                            \
        acc[mf][NF] = __builtin_amdgcn_mfma_f32_16x16x32_bf16(ah[mf], bl[NF], acc[mf][NF], 0, 0, 0); \
    _Pragma("unroll")                                                         \
    for (int mf = 0; mf < 4; ++mf)                                            \
        acc[mf][NF] = __builtin_amdgcn_mfma_f32_16x16x32_bf16(al[mf], bh[NF], acc[mf][NF], 0, 0, 0); \
    _Pragma("unroll")                                                         \
    for (int mf = 0; mf < 4; ++mf)                                            \
        acc[mf][NF] = __builtin_amdgcn_mfma_f32_16x16x32_bf16(ah[mf], bh[NF], acc[mf][NF], 0, 0, 0); \
    __builtin_amdgcn_s_setprio(0);                                            \
} while (0)
#define MCLM(MF) do {                                                         \
    __builtin_amdgcn_s_setprio(1);                                            \
    _Pragma("unroll")                                                         \
    for (int nf = 0; nf < 4; ++nf)                                            \
        acc[4 + (MF)][nf] = __builtin_amdgcn_mfma_f32_16x16x32_bf16(ah[MF], bl[nf], acc[4 + (MF)][nf], 0, 0, 0); \
    _Pragma("unroll")                                                         \
    for (int nf = 0; nf < 4; ++nf)                                            \
        acc[4 + (MF)][nf] = __builtin_amdgcn_mfma_f32_16x16x32_bf16(al[MF], bh[nf], acc[4 + (MF)][nf], 0, 0, 0); \
    _Pragma("unroll")                                                         \
    for (int nf = 0; nf < 4; ++nf)                                            \
        acc[4 + (MF)][nf] = __builtin_amdgcn_mfma_f32_16x16x32_bf16(ah[MF], bh[nf], acc[4 + (MF)][nf], 0, 0, 0); \
    __builtin_amdgcn_s_setprio(0);                                            \
} while (0)

#define TILE_BODY(KT, RB) do {                                                \
    const int B0 = (RB) * 65536;                                              \
    const int B1 = ((RB) ^ 1) * 65536;                                        \
    asm volatile("s_waitcnt vmcnt(0) lgkmcnt(0)" ::: "memory");               \
    __builtin_amdgcn_s_barrier();                                             \
    SB;                                                                       \
    const bool pf = (KT) + 1 < NKT;                                           \
    float4 fa, fb;                                                            \
    if (pf) {                                                                 \
        const float* ga_ = gA + ((KT) + 1) * 32;                              \
        fa = *(const float4*)(ga_);                                           \
        fb = *(const float4*)(ga_ + 4);                                       \
        const int kb_ = ((KT) + 1) * 64;                                      \
        GL_LDS16(gBh + kb_,         ldst + B1 + 32768);                       \
        GL_LDS16(gBh + RSTEP + kb_, ldst + B1 + 40960);                       \
        GL_LDS16(gBl + kb_,         ldst + B1 + 49152);                       \
        GL_LDS16(gBl + RSTEP + kb_, ldst + B1 + 57344);                       \
    }                                                                         \
    RD_B(0);                                                                  \
    RD_A(0, 0); RD_A(1, 0); RD_A(2, 0); RD_A(3, 0);                           \
    RD_B(1);                                                                  \
    SB;                                                                       \
    MCLN(0); SB;                                                              \
    RD_B(2); SB;                                                              \
    MCLN(1); SB;                                                              \
    RD_B(3); SB;                                                              \
    MCLN(2); SB;                                                              \
    MCLN(3); SB;                                                              \
    RD_A(0, 4096); RD_A(1, 4096); SB;                                         \
    MCLM(0); SB;                                                              \
    if (pf) {                                                                 \
        short8 hv, lv;                                                        \
        split8(fa, fb, hv, lv);                                               \
        *(short8*)(smem + B1 + aw0) = hv;                                     \
        *(short8*)(smem + B1 + 16384 + aw0) = lv;                             \
        const float* ga_ = gA + ((KT) + 1) * 32 + 8;                          \
        fa = *(const float4*)(ga_);                                           \
        fb = *(const float4*)(ga_ + 4);                                       \
    }                                                                         \
    SB;                                                                       \
    RD_A(2, 4096); SB;                                                        \
    MCLM(1); SB;                                                              \
    RD_A(3, 4096); SB;                                                        \
    MCLM(2); SB;                                                              \
    if (pf) {                                                                 \
        short8 hv, lv;                                                        \
        split8(fa, fb, hv, lv);                                               \
        *(short8*)(smem + B1 + aw1) = hv;                                     \
        *(short8*)(smem + B1 + 16384 + aw1) = lv;                             \
    }                                                                         \
    SB;                                                                       \
    MCLM(3);                                                                  \
} while (0)

#pragma unroll 1
    for (int kt = 0; kt < NKT; kt += 2) {
        TILE_BODY(kt, 0);
        TILE_BODY(kt + 1, 1);
    }

    // ---- fused epilogue: per-(row, chunk) online-softmax partials ----
    // C/D layout: col = lane&15 (ml), row = kh*4 + reg  [m89/m91].
    // chunk = nt*4 + wc covers cols chunk*64 .. +63; stats reduced across
    // the 16-lane half-group (shfl_xor 8,4,2,1 stays in group), f32 trees.
    const int chunk = nt * 4 + wc;
    const int colbase = n0 + wc * 64;
    float bcol[4]; bool bval[4];
#pragma unroll
    for (int ni = 0; ni < 4; ++ni) {
        const int col = colbase + ni * 16 + ml;
        bval[ni] = (col < N_COLS);
        bcol[ni] = bval[ni] ? bias[col] : 0.f;
    }
#pragma unroll
    for (int mi = 0; mi < 8; ++mi) {
        const int rbase = m0 + wr * 128 + (mi >> 2) * 64 + (mi & 3) * 16 + kh * 4;
#pragma unroll
        for (int r = 0; r < 4; ++r) {
            float x[4];
            float bv = -3.0e38f; int bi = 0;
#pragma unroll
            for (int ni = 0; ni < 4; ++ni) {
                x[ni] = acc[mi][ni][r] + bcol[ni];
                const int col = colbase + ni * 16 + ml;
                if (bval[ni] && x[ni] > bv) { bv = x[ni]; bi = col; }
            }
#pragma unroll
            for (int s = 8; s > 0; s >>= 1) {
                const float ov = __shfl_xor(bv, s);
                const int   oi = __shfl_xor(bi, s);
                if (ov > bv || (ov == bv && oi < bi)) { bv = ov; bi = oi; }
            }
            float S = 0.f, T = 0.f;
#pragma unroll
            for (int ni = 0; ni < 4; ++ni) {
                if (bval[ni]) {
                    const float d = x[ni] - bv;         // <= 0
                    const float e = __expf(d);          // HW v_exp_f32
                    S += e;
                    T = fmaf(e, d, T);
                }
            }
#pragma unroll
            for (int s = 8; s > 0; s >>= 1) {
                S += __shfl_xor(S, s);
                T += __shfl_xor(T, s);
            }
            if (ml == 0) {
                double* pp = part + ((size_t)(rbase + r) * 16 + chunk) * 4;
                pp[0] = (double)S; pp[1] = (double)T;
                pp[2] = (double)bv; pp[3] = (double)bi;
            }
        }
    }
#undef TILE_BODY
#undef MCLM
#undef MCLN
#undef RD_A
#undef RD_B
#undef SB
#undef FRAG
}

// ------------- per-batch: merge partials, stable sort by entropy, tie loop -------------
__global__ __launch_bounds__(64)
void vote_kernel(const double* __restrict__ part, float* __restrict__ out)
{
    __shared__ double e[NUM_TTA];
    __shared__ int    sv[NUM_TTA];
    __shared__ float  counts[N_COLS];

    const int b = blockIdx.x;
    const int t = threadIdx.x;
    const int row = b * NUM_TTA + t;

    // ---- merge 16 chunk partials (ascending chunk = ascending cols) ----
    const double* pp = part + (size_t)row * 64;
    float m = -3.0e38f; int amax = 0;
#pragma unroll
    for (int c = 0; c < 16; ++c) {
        const float pm = (float)pp[c * 4 + 2];
        const int   pa = (int)pp[c * 4 + 3];
        if (pm > m) { m = pm; amax = pa; }   // strict > : earlier chunk (lower col) wins ties
    }
    double S = 0.0, T = 0.0;
#pragma unroll
    for (int c = 0; c < 16; ++c) {
        const double dm = (double)((float)pp[c * 4 + 2]) - (double)m;
        const double f  = exp_neg(dm);
        S += pp[c * 4 + 0] * f;
        T += (pp[c * 4 + 1] + dm * pp[c * 4 + 0]) * f;
    }
    e[t] = log(S) - T / S;
    const int myv = amax;
    for (int c = t; c < N_COLS; c += NUM_TTA) counts[c] = 0.f;
    __syncthreads();

    const double et = e[t];
    int rank = 0;
#pragma unroll
    for (int i = 0; i < NUM_TTA; ++i) {
        const double ei = e[i];
        rank += (ei < et) || (ei == et && i < t);
    }
    sv[rank] = myv;
    __syncthreads();

    if (t == 0) {
        for (int j = 0; j < KEPT; ++j) counts[sv[j]] += 1.f;
        float Mv = 0.f; int Tc = 0;
        for (int j = 0; j < KEPT; ++j) {
            const int c = sv[j];
            bool dup = false;
            for (int q = 0; q < j; ++q) dup = dup || (sv[q] == c);
            if (dup) continue;
            const float cv = counts[c];
            if (cv > Mv) { Mv = cv; Tc = 1; }
            else if (cv == Mv) { Tc += 1; }
        }
        for (int i = 0; i < NUM_TTA - KEPT; ++i) {
            if (Tc <= 1) break;
            const int c = sv[KEPT + i];
            const float oldc = counts[c];
            counts[c] = oldc + 1.f;
            if (oldc == Mv)            { Mv += 1.f; Tc = 1; }
            else if (oldc + 1.f == Mv) { Tc += 1; }
        }
    }
    __syncthreads();

    const size_t o0 = (size_t)b * N_COLS;
    for (int c = t; c < N_COLS; c += NUM_TTA)
        out[o0 + c] = logf(counts[c] * (1.f / 64.f) + 1e-8f);
}

// -------------------------------- launch --------------------------------
extern "C" void kernel_launch(void* const* d_in, const int* in_sizes, int n_in,
                              void* d_out, int out_size, void* d_ws, size_t ws_size,
                              hipStream_t stream) {
    const float* x    = (const float*)d_in[0];
    const float* Wm   = (const float*)d_in[1];
    const float* bias = (const float*)d_in[2];
    float* out = (float*)d_out;

    // ws layout: part f64[16384*16*4] (8 MB) | Wh,Wl bf16[1024*4096]
    char* p = (char*)d_ws;
    double* part = (double*)p;                     p += (size_t)M_ROWS * 16 * 4 * 8;
    unsigned short* Wh = (unsigned short*)p;       p += (size_t)N_PAD * K_DIM * 2;
    unsigned short* Wl = (unsigned short*)p;       p += (size_t)N_PAD * K_DIM * 2;

    split_w<<<dim3(K_DIM / 32, N_PAD / 32), dim3(32, 32), 0, stream>>>(Wm, Wh, Wl);

    const int m_tiles = M_ROWS / 256;   // 64, divisible by 8
    gemm_mfma<<<4 * m_tiles, 512, 0, stream>>>(
        x, Wh, Wl, bias, part, m_tiles);
    vote_kernel<<<BATCH, NUM_TTA, 0, stream>>>(part, out);
}